// Round 3
// baseline (14850.563 us; speedup 1.0000x reference)
//
#include <hip/hip_runtime.h>
#include <math.h>

// Problem dims (fixed by reference)
#define BB 32
#define CC 8
#define TT 64
#define FF 256
#define HH 512
#define G3 1536
#define NSEQ 256            // BB*CC
#define MROWS 16384         // NSEQ*TT

typedef _Float16 f16x8 __attribute__((ext_vector_type(8)));
typedef float f32x4 __attribute__((ext_vector_type(4)));

// ---------------- input GEMM: C[M][N] = A[M][K] @ W[N][K]^T + bias[N] ----------------
#define TMg 128
#define TNg 128
#define TKg 16

__global__ __launch_bounds__(256) void gemm_bias(
    const float* __restrict__ A, const float* __restrict__ W,
    const float* __restrict__ bias, float* __restrict__ C,
    int M, int N, int K)
{
  __shared__ float As[TKg][TMg + 4];
  __shared__ float Ws[TKg][TNg + 4];
  const int bm = blockIdx.y * TMg;
  const int bn = blockIdx.x * TNg;
  const int tid = threadIdx.x;
  const int tx = tid & 15;
  const int ty = tid >> 4;
  float acc[8][8];
#pragma unroll
  for (int i = 0; i < 8; ++i)
#pragma unroll
    for (int j = 0; j < 8; ++j) acc[i][j] = 0.f;

  for (int k0 = 0; k0 < K; k0 += TKg) {
    __syncthreads();
#pragma unroll
    for (int i = 0; i < 8; ++i) {
      int e = i * 256 + tid;
      int r = e >> 4;
      int c = e & 15;
      As[c][r] = A[(size_t)(bm + r) * K + (k0 + c)];
      Ws[c][r] = W[(size_t)(bn + r) * K + (k0 + c)];
    }
    __syncthreads();
#pragma unroll
    for (int k = 0; k < TKg; ++k) {
      float a[8], w[8];
#pragma unroll
      for (int i = 0; i < 8; ++i) a[i] = As[k][ty * 8 + i];
#pragma unroll
      for (int j = 0; j < 8; ++j) w[j] = Ws[k][tx + 16 * j];
#pragma unroll
      for (int i = 0; i < 8; ++i)
#pragma unroll
        for (int j = 0; j < 8; ++j) acc[i][j] = fmaf(a[i], w[j], acc[i][j]);
    }
  }
#pragma unroll
  for (int i = 0; i < 8; ++i) {
    size_t m = (size_t)(bm + ty * 8 + i);
#pragma unroll
    for (int j = 0; j < 8; ++j) {
      int n = bn + tx + 16 * j;
      C[m * N + n] = acc[i][j] + bias[n];
    }
  }
}

// ---------------- pack Whh[G3][HH] fp32 -> fp16 hi/lo B-fragments ----------------
// Layout: P[tile(96)][kc(16)][plane(2)][lane(64)][8 f16]
// B-frag mapping (16x16x32): n = lane&15 (row of Whh within tile), k = kc*32 + (lane>>4)*8 + i
// lo plane scaled by 2048 to stay in fp16 normal range.
__global__ __launch_bounds__(256) void pack_whh(
    const float* __restrict__ W, _Float16* __restrict__ P)
{
  int id = blockIdx.x * 256 + threadIdx.x;    // 0 .. 98303
  int lane = id & 63;
  int kc = (id >> 6) & 15;
  int tile = id >> 10;                        // 0..95
  int row = tile * 16 + (lane & 15);
  int k0 = kc * 32 + ((lane >> 4) * 8);
  const float* src = W + (size_t)row * HH + k0;
  f16x8 hi, lo;
#pragma unroll
  for (int i = 0; i < 8; ++i) {
    float w = src[i];
    _Float16 h = (_Float16)w;
    hi[i] = h;
    lo[i] = (_Float16)((w - (float)h) * 2048.0f);
  }
  size_t base = ((size_t)(tile * 16 + kc) * 2) * 512 + (size_t)lane * 8;
  *reinterpret_cast<f16x8*>(P + base) = hi;
  *reinterpret_cast<f16x8*>(P + base + 512) = lo;
}

// ---------------- MFMA recurrent scan ----------------
// 16 blocks x 16 seqs. 8 waves x 12 N-tiles (of 96). h fp16 in LDS.
// Per step: preact[16][1536] = h[16][512] @ W^T via 2-plane fp16 MFMA, then gates.
#define SPB2 16

__global__ __launch_bounds__(512) void gru_scan_mfma(
    const float* __restrict__ gi,      // [NSEQ][TT][G3]
    const _Float16* __restrict__ packW,
    const float* __restrict__ bhh,     // [G3]
    float* __restrict__ hfin,          // [NSEQ][HH]
    float* __restrict__ yout)          // [NSEQ][TT][HH] or nullptr
{
  __shared__ _Float16 hs16[SPB2][528];      // 16.9 KB, padded stride
  __shared__ float pre[SPB2][1540];         // 98.6 KB, padded stride

  const int tid = threadIdx.x;
  const int lane = tid & 63;
  const int wid = tid >> 6;
  const int seq0 = blockIdx.x * SPB2;

  // zero h
  for (int e = tid; e < SPB2 * 528; e += 512)
    hs16[e / 528][e % 528] = (_Float16)0.f;

  // epilogue-role constants: thread j owns column j
  const int j = tid;
  const float bh0 = bhh[j];
  const float bh1 = bhh[HH + j];
  const float bh2 = bhh[2 * HH + j];
  float hold[SPB2];
#pragma unroll
  for (int s = 0; s < SPB2; ++s) hold[s] = 0.f;

  // matmul-role constants
  const int arow = lane & 15;
  const int agrp = lane >> 4;
  const int dcol = lane & 15;
  const int mrow = (lane >> 4) * 4;

  __syncthreads();

  for (int t = 0; t < TT; ++t) {
    // ---- matmul phase: pre = h @ W^T ----
    f16x8 af[16];
#pragma unroll
    for (int kc = 0; kc < 16; ++kc)
      af[kc] = *reinterpret_cast<const f16x8*>(&hs16[arow][kc * 32 + agrp * 8]);

#pragma unroll
    for (int tp = 0; tp < 6; ++tp) {
      const int t0 = wid * 12 + tp * 2;
      const int t1 = t0 + 1;
      f32x4 aH0 = {0.f, 0.f, 0.f, 0.f}, aL0 = {0.f, 0.f, 0.f, 0.f};
      f32x4 aH1 = {0.f, 0.f, 0.f, 0.f}, aL1 = {0.f, 0.f, 0.f, 0.f};
#pragma unroll
      for (int kc = 0; kc < 16; ++kc) {
        size_t e0 = ((size_t)(t0 * 16 + kc) * 2) * 512 + (size_t)lane * 8;
        size_t e1 = ((size_t)(t1 * 16 + kc) * 2) * 512 + (size_t)lane * 8;
        f16x8 bh_0 = *reinterpret_cast<const f16x8*>(packW + e0);
        f16x8 bl_0 = *reinterpret_cast<const f16x8*>(packW + e0 + 512);
        f16x8 bh_1 = *reinterpret_cast<const f16x8*>(packW + e1);
        f16x8 bl_1 = *reinterpret_cast<const f16x8*>(packW + e1 + 512);
        aH0 = __builtin_amdgcn_mfma_f32_16x16x32_f16(af[kc], bh_0, aH0, 0, 0, 0);
        aH1 = __builtin_amdgcn_mfma_f32_16x16x32_f16(af[kc], bh_1, aH1, 0, 0, 0);
        aL0 = __builtin_amdgcn_mfma_f32_16x16x32_f16(af[kc], bl_0, aL0, 0, 0, 0);
        aL1 = __builtin_amdgcn_mfma_f32_16x16x32_f16(af[kc], bl_1, aL1, 0, 0, 0);
      }
      const int n0 = t0 * 16 + dcol;
      const int n1 = t1 * 16 + dcol;
#pragma unroll
      for (int r = 0; r < 4; ++r) {
        pre[mrow + r][n0] = aH0[r] + aL0[r] * (1.0f / 2048.0f);
        pre[mrow + r][n1] = aH1[r] + aL1[r] * (1.0f / 2048.0f);
      }
    }

    __syncthreads();

    // ---- gate epilogue: thread j handles column j for all 16 seqs ----
#pragma unroll
    for (int s = 0; s < SPB2; ++s) {
      const float* gib = gi + ((size_t)(seq0 + s) * TT + t) * G3;
      float hr = pre[s][j] + bh0;
      float hz = pre[s][HH + j] + bh1;
      float hn = pre[s][2 * HH + j] + bh2;
      float ir = gib[j];
      float iz = gib[HH + j];
      float inn = gib[2 * HH + j];
      float r = __builtin_amdgcn_rcpf(1.f + __expf(-(ir + hr)));
      float z = __builtin_amdgcn_rcpf(1.f + __expf(-(iz + hz)));
      float ex = __expf(2.f * (inn + r * hn));
      float nn = 1.f - 2.f * __builtin_amdgcn_rcpf(ex + 1.f);
      float hnew = nn + z * (hold[s] - nn);
      hold[s] = hnew;
      hs16[s][j] = (_Float16)hnew;
      if (yout) yout[((size_t)(seq0 + s) * TT + t) * HH + j] = hnew;
    }
    __syncthreads();
  }

#pragma unroll
  for (int s = 0; s < SPB2; ++s)
    hfin[(size_t)(seq0 + s) * HH + j] = hold[s];
}

// ---------------- fallback fp32 scan (round-1, row-streaming) ----------------
#define QS 4
#define SCTH 512
__global__ __launch_bounds__(SCTH) void gru_scan2f(
    const float* __restrict__ gi, const float* __restrict__ W,
    const float* __restrict__ bhh, float* __restrict__ hfin,
    float* __restrict__ yout)
{
  __shared__ __align__(16) float hs[HH][QS];
  const int col = threadIdx.x;
  const int seq0 = blockIdx.x * QS;
  const float bh0 = bhh[col];
  const float bh1 = bhh[HH + col];
  const float bh2 = bhh[2 * HH + col];
  const float* w0p = W + (size_t)col * HH;
  const float* w1p = W + (size_t)(HH + col) * HH;
  const float* w2p = W + (size_t)(2 * HH + col) * HH;

  *reinterpret_cast<float4*>(&hs[col][0]) = make_float4(0.f, 0.f, 0.f, 0.f);
  __syncthreads();

  for (int t = 0; t < TT; ++t) {
    float acc0[QS], acc1[QS], acc2[QS];
#pragma unroll
    for (int s = 0; s < QS; ++s) { acc0[s] = bh0; acc1[s] = bh1; acc2[s] = bh2; }
    float4 ho = *reinterpret_cast<const float4*>(&hs[col][0]);
    float hold[QS] = {ho.x, ho.y, ho.z, ho.w};
#pragma unroll 2
    for (int k0 = 0; k0 < HH; k0 += 4) {
      float w[3][4];
      float4 a = *reinterpret_cast<const float4*>(&w0p[k0]);
      w[0][0] = a.x; w[0][1] = a.y; w[0][2] = a.z; w[0][3] = a.w;
      float4 b = *reinterpret_cast<const float4*>(&w1p[k0]);
      w[1][0] = b.x; w[1][1] = b.y; w[1][2] = b.z; w[1][3] = b.w;
      float4 c = *reinterpret_cast<const float4*>(&w2p[k0]);
      w[2][0] = c.x; w[2][1] = c.y; w[2][2] = c.z; w[2][3] = c.w;
#pragma unroll
      for (int kk = 0; kk < 4; ++kk) {
        float4 h4 = *reinterpret_cast<const float4*>(&hs[k0 + kk][0]);
        float hq[4] = {h4.x, h4.y, h4.z, h4.w};
#pragma unroll
        for (int s = 0; s < QS; ++s) {
          acc0[s] = fmaf(hq[s], w[0][kk], acc0[s]);
          acc1[s] = fmaf(hq[s], w[1][kk], acc1[s]);
          acc2[s] = fmaf(hq[s], w[2][kk], acc2[s]);
        }
      }
    }
    __syncthreads();
    float hnew[QS];
#pragma unroll
    for (int s = 0; s < QS; ++s) {
      size_t grow = ((size_t)(seq0 + s) * TT + t) * G3;
      float ir = gi[grow + col];
      float iz = gi[grow + HH + col];
      float inn = gi[grow + 2 * HH + col];
      float r = 1.f / (1.f + expf(-(ir + acc0[s])));
      float z = 1.f / (1.f + expf(-(iz + acc1[s])));
      float nn = tanhf(inn + r * acc2[s]);
      hnew[s] = (1.f - z) * nn + z * hold[s];
      if (yout) yout[((size_t)(seq0 + s) * TT + t) * HH + col] = hnew[s];
    }
    *reinterpret_cast<float4*>(&hs[col][0]) =
        make_float4(hnew[0], hnew[1], hnew[2], hnew[3]);
    __syncthreads();
  }
#pragma unroll
  for (int s = 0; s < QS; ++s)
    hfin[(size_t)(seq0 + s) * HH + col] = hs[col][s];
}

// ---------------- final FC + channel mean ----------------
__global__ __launch_bounds__(256) void fc_mean(
    const float* __restrict__ hfin, const float* __restrict__ fcW,
    const float* __restrict__ fcb, float* __restrict__ out)
{
  __shared__ float red[256];
  const int b = blockIdx.x;
  const int tid = threadIdx.x;
  float sum = 0.f;
  for (int e = tid; e < CC * HH; e += 256) {
    int c = e >> 9;
    int k = e & (HH - 1);
    sum += hfin[(size_t)(b * CC + c) * HH + k] * fcW[k];
  }
  red[tid] = sum;
  __syncthreads();
  for (int w = 128; w > 0; w >>= 1) {
    if (tid < w) red[tid] += red[tid + w];
    __syncthreads();
  }
  if (tid == 0) out[b] = red[0] * (1.f / CC) + fcb[0];
}

extern "C" void kernel_launch(void* const* d_in, const int* in_sizes, int n_in,
                              void* d_out, int out_size, void* d_ws, size_t ws_size,
                              hipStream_t stream)
{
  const float* x    = (const float*)d_in[0];
  const float* Wih0 = (const float*)d_in[1];
  const float* Whh0 = (const float*)d_in[2];
  const float* bih0 = (const float*)d_in[3];
  const float* bhh0 = (const float*)d_in[4];
  const float* Wih1 = (const float*)d_in[5];
  const float* Whh1 = (const float*)d_in[6];
  const float* bih1 = (const float*)d_in[7];
  const float* bhh1 = (const float*)d_in[8];
  const float* fcW  = (const float*)d_in[9];
  const float* fcb  = (const float*)d_in[10];
  float* out = (float*)d_out;

  // ws layout:
  //   gi   [MROWS][G3] fp32   100,663,296 @ 0
  //   y0   [MROWS][HH] fp32    33,554,432 @ 100,663,296
  //   hfin [NSEQ][HH]  fp32       524,288 @ 134,217,728
  //   pack fp16 (shared, layer0 then layer1)  3,145,728 @ 134,742,016
  char* ws = (char*)d_ws;
  float* gibuf = (float*)ws;
  float* y0    = (float*)(ws + 100663296ull);
  float* hfin  = (float*)(ws + 134217728ull);
  _Float16* packb = (_Float16*)(ws + 134742016ull);
  const bool mfma_ok = (ws_size >= 137887744ull);

  // layer 0 input GEMM
  gemm_bias<<<dim3(G3 / TNg, MROWS / TMg), 256, 0, stream>>>(x, Wih0, bih0, gibuf, MROWS, G3, FF);

  if (mfma_ok) {
    pack_whh<<<dim3(384), 256, 0, stream>>>(Whh0, packb);
    gru_scan_mfma<<<dim3(NSEQ / SPB2), 512, 0, stream>>>(gibuf, packb, bhh0, hfin, y0);
  } else {
    gru_scan2f<<<dim3(NSEQ / QS), SCTH, 0, stream>>>(gibuf, Whh0, bhh0, hfin, y0);
  }

  // layer 1 input GEMM (gi reused)
  gemm_bias<<<dim3(G3 / TNg, MROWS / TMg), 256, 0, stream>>>(y0, Wih1, bih1, gibuf, MROWS, G3, HH);

  if (mfma_ok) {
    pack_whh<<<dim3(384), 256, 0, stream>>>(Whh1, packb);
    gru_scan_mfma<<<dim3(NSEQ / SPB2), 512, 0, stream>>>(gibuf, packb, bhh1, hfin, nullptr);
  } else {
    gru_scan2f<<<dim3(NSEQ / QS), SCTH, 0, stream>>>(gibuf, Whh1, bhh1, hfin, nullptr);
  }

  fc_mean<<<dim3(BB), 256, 0, stream>>>(hfin, fcW, fcb, out);
}

// Round 4
// 5821.108 us; speedup vs baseline: 2.5512x; 2.5512x over previous
//
#include <hip/hip_runtime.h>
#include <math.h>

// Problem dims (fixed by reference)
#define BB 32
#define CC 8
#define TT 64
#define FF 256
#define HH 512
#define G3 1536
#define NSEQ 256            // BB*CC
#define MROWS 16384         // NSEQ*TT

typedef _Float16 f16x8 __attribute__((ext_vector_type(8)));
typedef float f32x4 __attribute__((ext_vector_type(4)));

// ---------------- input GEMM: C[M][N] = A[M][K] @ W[N][K]^T + bias[N] ----------------
#define TMg 128
#define TNg 128
#define TKg 16

__global__ __launch_bounds__(256) void gemm_bias(
    const float* __restrict__ A, const float* __restrict__ W,
    const float* __restrict__ bias, float* __restrict__ C,
    int M, int N, int K)
{
  __shared__ float As[TKg][TMg + 4];
  __shared__ float Ws[TKg][TNg + 4];
  const int bm = blockIdx.y * TMg;
  const int bn = blockIdx.x * TNg;
  const int tid = threadIdx.x;
  const int tx = tid & 15;
  const int ty = tid >> 4;
  float acc[8][8];
#pragma unroll
  for (int i = 0; i < 8; ++i)
#pragma unroll
    for (int j = 0; j < 8; ++j) acc[i][j] = 0.f;

  for (int k0 = 0; k0 < K; k0 += TKg) {
    __syncthreads();
#pragma unroll
    for (int i = 0; i < 8; ++i) {
      int e = i * 256 + tid;
      int r = e >> 4;
      int c = e & 15;
      As[c][r] = A[(size_t)(bm + r) * K + (k0 + c)];
      Ws[c][r] = W[(size_t)(bn + r) * K + (k0 + c)];
    }
    __syncthreads();
#pragma unroll
    for (int k = 0; k < TKg; ++k) {
      float a[8], w[8];
#pragma unroll
      for (int i = 0; i < 8; ++i) a[i] = As[k][ty * 8 + i];
#pragma unroll
      for (int j = 0; j < 8; ++j) w[j] = Ws[k][tx + 16 * j];
#pragma unroll
      for (int i = 0; i < 8; ++i)
#pragma unroll
        for (int j = 0; j < 8; ++j) acc[i][j] = fmaf(a[i], w[j], acc[i][j]);
    }
  }
#pragma unroll
  for (int i = 0; i < 8; ++i) {
    size_t m = (size_t)(bm + ty * 8 + i);
#pragma unroll
    for (int j = 0; j < 8; ++j) {
      int n = bn + tx + 16 * j;
      C[m * N + n] = acc[i][j] + bias[n];
    }
  }
}

// ---------------- pack Whh[G3][HH] fp32 -> single fp16 plane, B-fragment order --------
// P[tile(96)][kc(16)][lane(64)][8 f16]
// B-frag (16x16x32_f16): n = lane&15 (Whh row within tile), k = kc*32 + (lane>>4)*8 + i
__global__ __launch_bounds__(256) void pack_whh(
    const float* __restrict__ W, _Float16* __restrict__ P)
{
  int id = blockIdx.x * 256 + threadIdx.x;    // 0 .. 98303
  int lane = id & 63;
  int kc = (id >> 6) & 15;
  int tile = id >> 10;                        // 0..95
  int row = tile * 16 + (lane & 15);
  int k0 = kc * 32 + ((lane >> 4) * 8);
  const float* src = W + (size_t)row * HH + k0;
  f16x8 hi;
#pragma unroll
  for (int i = 0; i < 8; ++i) hi[i] = (_Float16)src[i];
  *reinterpret_cast<f16x8*>(P + ((size_t)(tile * 16 + kc) * 64 + lane) * 8) = hi;
}

// ---------------- MFMA recurrent scan ----------------
// 16 blocks x 16 seqs. 8 waves x 12 N-tiles (of 96). h fp16 in LDS.
// Weights stream from L2 (kept resident via nontemporal gi/yout), register
// double-buffered 16 fragments deep.
#define SPB2 16

__global__ __launch_bounds__(512) void gru_scan_mfma(
    const float* __restrict__ gi,      // [NSEQ][TT][G3]
    const _Float16* __restrict__ packW,
    const float* __restrict__ bhh,     // [G3]
    float* __restrict__ hfin,          // [NSEQ][HH]
    float* __restrict__ yout)          // [NSEQ][TT][HH] or nullptr
{
  __shared__ _Float16 hs16[SPB2][536];      // 17.2 KB (stride 536: bank-spread)
  __shared__ float pre[SPB2][1540];         // 98.6 KB

  const int tid = threadIdx.x;
  const int lane = tid & 63;
  const int wid = tid >> 6;
  const int seq0 = blockIdx.x * SPB2;

  for (int e = tid; e < SPB2 * 536; e += 512)
    hs16[e / 536][e % 536] = (_Float16)0.f;

  const int j = tid;                       // epilogue column
  const float bh0 = bhh[j];
  const float bh1 = bhh[HH + j];
  const float bh2 = bhh[2 * HH + j];
  float hold[SPB2];
#pragma unroll
  for (int s = 0; s < SPB2; ++s) hold[s] = 0.f;

  const int arow = lane & 15;
  const int agrp = lane >> 4;
  const int dcol = lane & 15;
  const int mrow = (lane >> 4) * 4;

  __syncthreads();

  for (int t = 0; t < TT; ++t) {
    // ---- matmul phase: pre = h @ W^T (single fp16 plane) ----
    f16x8 af[16];
#pragma unroll
    for (int kc = 0; kc < 16; ++kc)
      af[kc] = *reinterpret_cast<const f16x8*>(&hs16[arow][kc * 32 + agrp * 8]);

    f16x8 bufA[16], bufB[16];
    const size_t laneoff = (size_t)lane * 8;

    // load first tile of this wave
    {
      const int tt = wid * 12;
      const _Float16* src = packW + (size_t)tt * 16 * 512 + laneoff;
#pragma unroll
      for (int kc = 0; kc < 16; ++kc)
        bufA[kc] = *reinterpret_cast<const f16x8*>(src + (size_t)kc * 512);
    }

    auto body = [&](f16x8 (&cur)[16], f16x8 (&nxt)[16], int i) {
      // prefetch next tile (16 dwordx4 in flight during the MFMA chain)
      if (i < 11) {
        const int tn = wid * 12 + i + 1;
        const _Float16* src = packW + (size_t)tn * 16 * 512 + laneoff;
#pragma unroll
        for (int kc = 0; kc < 16; ++kc)
          nxt[kc] = *reinterpret_cast<const f16x8*>(src + (size_t)kc * 512);
      }
      f32x4 acc0 = {0.f, 0.f, 0.f, 0.f};
      f32x4 acc1 = {0.f, 0.f, 0.f, 0.f};
#pragma unroll
      for (int kc = 0; kc < 16; kc += 2) {
        acc0 = __builtin_amdgcn_mfma_f32_16x16x32_f16(af[kc], cur[kc], acc0, 0, 0, 0);
        acc1 = __builtin_amdgcn_mfma_f32_16x16x32_f16(af[kc + 1], cur[kc + 1], acc1, 0, 0, 0);
      }
      const int n0 = (wid * 12 + i) * 16 + dcol;
#pragma unroll
      for (int r = 0; r < 4; ++r)
        pre[mrow + r][n0] = acc0[r] + acc1[r];
    };

#pragma unroll
    for (int ii = 0; ii < 6; ++ii) {
      body(bufA, bufB, 2 * ii);
      body(bufB, bufA, 2 * ii + 1);
    }

    __syncthreads();

    // ---- gate epilogue: thread j handles column j for all 16 seqs ----
#pragma unroll
    for (int s = 0; s < SPB2; ++s) {
      const float* gib = gi + ((size_t)(seq0 + s) * TT + t) * G3;
      float ir  = __builtin_nontemporal_load(gib + j);
      float iz  = __builtin_nontemporal_load(gib + HH + j);
      float inn = __builtin_nontemporal_load(gib + 2 * HH + j);
      float hr = pre[s][j] + bh0;
      float hz = pre[s][HH + j] + bh1;
      float hn = pre[s][2 * HH + j] + bh2;
      float r = __builtin_amdgcn_rcpf(1.f + __expf(-(ir + hr)));
      float z = __builtin_amdgcn_rcpf(1.f + __expf(-(iz + hz)));
      float ex = __expf(2.f * (inn + r * hn));
      float nn = 1.f - 2.f * __builtin_amdgcn_rcpf(ex + 1.f);
      float hnew = nn + z * (hold[s] - nn);
      hold[s] = hnew;
      hs16[s][j] = (_Float16)hnew;
      if (yout)
        __builtin_nontemporal_store(hnew, yout + ((size_t)(seq0 + s) * TT + t) * HH + j);
    }
    __syncthreads();
  }

#pragma unroll
  for (int s = 0; s < SPB2; ++s)
    hfin[(size_t)(seq0 + s) * HH + j] = hold[s];
}

// ---------------- fallback fp32 scan (row-streaming, no transpose needed) ----------------
#define QS 4
#define SCTH 512
__global__ __launch_bounds__(SCTH) void gru_scan2f(
    const float* __restrict__ gi, const float* __restrict__ W,
    const float* __restrict__ bhh, float* __restrict__ hfin,
    float* __restrict__ yout)
{
  __shared__ __align__(16) float hs[HH][QS];
  const int col = threadIdx.x;
  const int seq0 = blockIdx.x * QS;
  const float bh0 = bhh[col];
  const float bh1 = bhh[HH + col];
  const float bh2 = bhh[2 * HH + col];
  const float* w0p = W + (size_t)col * HH;
  const float* w1p = W + (size_t)(HH + col) * HH;
  const float* w2p = W + (size_t)(2 * HH + col) * HH;

  *reinterpret_cast<float4*>(&hs[col][0]) = make_float4(0.f, 0.f, 0.f, 0.f);
  __syncthreads();

  for (int t = 0; t < TT; ++t) {
    float acc0[QS], acc1[QS], acc2[QS];
#pragma unroll
    for (int s = 0; s < QS; ++s) { acc0[s] = bh0; acc1[s] = bh1; acc2[s] = bh2; }
    float4 ho = *reinterpret_cast<const float4*>(&hs[col][0]);
    float hold[QS] = {ho.x, ho.y, ho.z, ho.w};
#pragma unroll 2
    for (int k0 = 0; k0 < HH; k0 += 4) {
      float w[3][4];
      float4 a = *reinterpret_cast<const float4*>(&w0p[k0]);
      w[0][0] = a.x; w[0][1] = a.y; w[0][2] = a.z; w[0][3] = a.w;
      float4 b = *reinterpret_cast<const float4*>(&w1p[k0]);
      w[1][0] = b.x; w[1][1] = b.y; w[1][2] = b.z; w[1][3] = b.w;
      float4 c = *reinterpret_cast<const float4*>(&w2p[k0]);
      w[2][0] = c.x; w[2][1] = c.y; w[2][2] = c.z; w[2][3] = c.w;
#pragma unroll
      for (int kk = 0; kk < 4; ++kk) {
        float4 h4 = *reinterpret_cast<const float4*>(&hs[k0 + kk][0]);
        float hq[4] = {h4.x, h4.y, h4.z, h4.w};
#pragma unroll
        for (int s = 0; s < QS; ++s) {
          acc0[s] = fmaf(hq[s], w[0][kk], acc0[s]);
          acc1[s] = fmaf(hq[s], w[1][kk], acc1[s]);
          acc2[s] = fmaf(hq[s], w[2][kk], acc2[s]);
        }
      }
    }
    __syncthreads();
    float hnew[QS];
#pragma unroll
    for (int s = 0; s < QS; ++s) {
      size_t grow = ((size_t)(seq0 + s) * TT + t) * G3;
      float ir = gi[grow + col];
      float iz = gi[grow + HH + col];
      float inn = gi[grow + 2 * HH + col];
      float r = 1.f / (1.f + expf(-(ir + acc0[s])));
      float z = 1.f / (1.f + expf(-(iz + acc1[s])));
      float nn = tanhf(inn + r * acc2[s]);
      hnew[s] = (1.f - z) * nn + z * hold[s];
      if (yout) yout[((size_t)(seq0 + s) * TT + t) * HH + col] = hnew[s];
    }
    *reinterpret_cast<float4*>(&hs[col][0]) =
        make_float4(hnew[0], hnew[1], hnew[2], hnew[3]);
    __syncthreads();
  }
#pragma unroll
  for (int s = 0; s < QS; ++s)
    hfin[(size_t)(seq0 + s) * HH + col] = hs[col][s];
}

// ---------------- final FC + channel mean ----------------
__global__ __launch_bounds__(256) void fc_mean(
    const float* __restrict__ hfin, const float* __restrict__ fcW,
    const float* __restrict__ fcb, float* __restrict__ out)
{
  __shared__ float red[256];
  const int b = blockIdx.x;
  const int tid = threadIdx.x;
  float sum = 0.f;
  for (int e = tid; e < CC * HH; e += 256) {
    int c = e >> 9;
    int k = e & (HH - 1);
    sum += hfin[(size_t)(b * CC + c) * HH + k] * fcW[k];
  }
  red[tid] = sum;
  __syncthreads();
  for (int w = 128; w > 0; w >>= 1) {
    if (tid < w) red[tid] += red[tid + w];
    __syncthreads();
  }
  if (tid == 0) out[b] = red[0] * (1.f / CC) + fcb[0];
}

extern "C" void kernel_launch(void* const* d_in, const int* in_sizes, int n_in,
                              void* d_out, int out_size, void* d_ws, size_t ws_size,
                              hipStream_t stream)
{
  const float* x    = (const float*)d_in[0];
  const float* Wih0 = (const float*)d_in[1];
  const float* Whh0 = (const float*)d_in[2];
  const float* bih0 = (const float*)d_in[3];
  const float* bhh0 = (const float*)d_in[4];
  const float* Wih1 = (const float*)d_in[5];
  const float* Whh1 = (const float*)d_in[6];
  const float* bih1 = (const float*)d_in[7];
  const float* bhh1 = (const float*)d_in[8];
  const float* fcW  = (const float*)d_in[9];
  const float* fcb  = (const float*)d_in[10];
  float* out = (float*)d_out;

  // ws layout:
  //   gi   [MROWS][G3] fp32   100,663,296 @ 0
  //   y0   [MROWS][HH] fp32    33,554,432 @ 100,663,296
  //   hfin [NSEQ][HH]  fp32       524,288 @ 134,217,728
  //   pack fp16 1-plane         1,572,864 @ 134,742,016   (end 136,314,880)
  char* ws = (char*)d_ws;
  float* gibuf = (float*)ws;
  float* y0    = (float*)(ws + 100663296ull);
  float* hfin  = (float*)(ws + 134217728ull);
  _Float16* packb = (_Float16*)(ws + 134742016ull);
  const bool mfma_ok = (ws_size >= 136314880ull);

  // layer 0 input GEMM
  gemm_bias<<<dim3(G3 / TNg, MROWS / TMg), 256, 0, stream>>>(x, Wih0, bih0, gibuf, MROWS, G3, FF);

  if (mfma_ok) {
    pack_whh<<<dim3(384), 256, 0, stream>>>(Whh0, packb);
    gru_scan_mfma<<<dim3(NSEQ / SPB2), 512, 0, stream>>>(gibuf, packb, bhh0, hfin, y0);
  } else {
    gru_scan2f<<<dim3(NSEQ / QS), SCTH, 0, stream>>>(gibuf, Whh0, bhh0, hfin, y0);
  }

  // layer 1 input GEMM (gi reused)
  gemm_bias<<<dim3(G3 / TNg, MROWS / TMg), 256, 0, stream>>>(y0, Wih1, bih1, gibuf, MROWS, G3, HH);

  if (mfma_ok) {
    pack_whh<<<dim3(384), 256, 0, stream>>>(Whh1, packb);
    gru_scan_mfma<<<dim3(NSEQ / SPB2), 512, 0, stream>>>(gibuf, packb, bhh1, hfin, nullptr);
  } else {
    gru_scan2f<<<dim3(NSEQ / QS), SCTH, 0, stream>>>(gibuf, Whh1, bhh1, hfin, nullptr);
  }

  fc_mean<<<dim3(BB), 256, 0, stream>>>(hfin, fcW, fcb, out);
}

// Round 5
// 5775.918 us; speedup vs baseline: 2.5711x; 1.0078x over previous
//
#include <hip/hip_runtime.h>
#include <math.h>

// Problem dims (fixed by reference)
#define BB 32
#define CC 8
#define TT 64
#define FF 256
#define HH 512
#define G3 1536
#define NSEQ 256            // BB*CC
#define MROWS 16384         // NSEQ*TT

typedef _Float16 f16x8 __attribute__((ext_vector_type(8)));
typedef float f32x4 __attribute__((ext_vector_type(4)));

// ---------------- input GEMM: C[M][N] = A[M][K] @ W[N][K]^T + bias[N] ----------------
#define TMg 128
#define TNg 128
#define TKg 16

__global__ __launch_bounds__(256) void gemm_bias(
    const float* __restrict__ A, const float* __restrict__ W,
    const float* __restrict__ bias, float* __restrict__ C,
    int M, int N, int K)
{
  __shared__ float As[TKg][TMg + 4];
  __shared__ float Ws[TKg][TNg + 4];
  const int bm = blockIdx.y * TMg;
  const int bn = blockIdx.x * TNg;
  const int tid = threadIdx.x;
  const int tx = tid & 15;
  const int ty = tid >> 4;
  float acc[8][8];
#pragma unroll
  for (int i = 0; i < 8; ++i)
#pragma unroll
    for (int j = 0; j < 8; ++j) acc[i][j] = 0.f;

  for (int k0 = 0; k0 < K; k0 += TKg) {
    __syncthreads();
#pragma unroll
    for (int i = 0; i < 8; ++i) {
      int e = i * 256 + tid;
      int r = e >> 4;
      int c = e & 15;
      As[c][r] = A[(size_t)(bm + r) * K + (k0 + c)];
      Ws[c][r] = W[(size_t)(bn + r) * K + (k0 + c)];
    }
    __syncthreads();
#pragma unroll
    for (int k = 0; k < TKg; ++k) {
      float a[8], w[8];
#pragma unroll
      for (int i = 0; i < 8; ++i) a[i] = As[k][ty * 8 + i];
#pragma unroll
      for (int j = 0; j < 8; ++j) w[j] = Ws[k][tx + 16 * j];
#pragma unroll
      for (int i = 0; i < 8; ++i)
#pragma unroll
        for (int j = 0; j < 8; ++j) acc[i][j] = fmaf(a[i], w[j], acc[i][j]);
    }
  }
#pragma unroll
  for (int i = 0; i < 8; ++i) {
    size_t m = (size_t)(bm + ty * 8 + i);
#pragma unroll
    for (int j = 0; j < 8; ++j) {
      int n = bn + tx + 16 * j;
      C[m * N + n] = acc[i][j] + bias[n];
    }
  }
}

// ---------------- pack Whh[G3][HH] fp32 -> single fp16 plane, B-fragment order --------
// P[tile(96)][kc(16)][lane(64)][8 f16]
// B-frag (16x16x32_f16): n = lane&15 (Whh row within tile), k = kc*32 + (lane>>4)*8 + i
__global__ __launch_bounds__(256) void pack_whh(
    const float* __restrict__ W, _Float16* __restrict__ P)
{
  int id = blockIdx.x * 256 + threadIdx.x;    // 0 .. 98303
  int lane = id & 63;
  int kc = (id >> 6) & 15;
  int tile = id >> 10;                        // 0..95
  int row = tile * 16 + (lane & 15);
  int k0 = kc * 32 + ((lane >> 4) * 8);
  const float* src = W + (size_t)row * HH + k0;
  f16x8 hi;
#pragma unroll
  for (int i = 0; i < 8; ++i) hi[i] = (_Float16)src[i];
  *reinterpret_cast<f16x8*>(P + ((size_t)(tile * 16 + kc) * 64 + lane) * 8) = hi;
}

// ---------------- MFMA recurrent scan, REGISTER-RESIDENT WEIGHTS ----------------
// 16 blocks x 16 seqs x 1024 threads (16 waves, 4/SIMD forced).
// Wave w owns tiles {w, w+32, w+64, w+16, w+48, w+80}: the r/z/n gate tiles of
// column-groups w and w+16. Weights preloaded ONCE into wb[6][16] (384 VGPR).
// Gate epilogue is register-local per lane (D-frag cells of all 3 gates align).
// h state: fp16, LDS double-buffered, stride 520 (bank-conflict-free b128 reads).
#define SPB2 16
#define HSTR 520

__global__ __launch_bounds__(1024, 1) void gru_scan_mfma(
    const float* __restrict__ gi,      // [NSEQ][TT][G3]
    const _Float16* __restrict__ packW,
    const float* __restrict__ bhh,     // [G3]
    float* __restrict__ hfin,          // [NSEQ][HH]
    float* __restrict__ yout)          // [NSEQ][TT][HH] or nullptr
{
  __shared__ _Float16 hsbuf[2][SPB2][HSTR];   // 33.3 KB

  const int tid = threadIdx.x;
  const int lane = tid & 63;
  const int wid = tid >> 6;                   // 0..15
  const int seq0 = blockIdx.x * SPB2;

  const int arow = lane & 15;                 // A-frag row (seq)
  const int agrp = lane >> 4;
  const int dcol = lane & 15;                 // D-frag col within tile
  const int mrow = (lane >> 4) * 4;           // D-frag first row (seq)

  const int cg0 = wid * 16 + dcol;            // column group w
  const int cg1 = cg0 + 256;                  // column group w+16

  // ---- preload weights into registers: tiles {w, w+32, w+64, w+16, w+48, w+80} ----
  f16x8 wb[6][16];
  {
    const int tiles[6] = {wid, wid + 32, wid + 64, wid + 16, wid + 48, wid + 80};
#pragma unroll
    for (int i = 0; i < 6; ++i) {
      const _Float16* src = packW + ((size_t)tiles[i] * 16 * 64 + lane) * 8;
#pragma unroll
      for (int kc = 0; kc < 16; ++kc)
        wb[i][kc] = *reinterpret_cast<const f16x8*>(src + (size_t)kc * 64 * 8);
    }
  }

  // biases for this lane's two columns, all 3 gates
  const float bhr0 = bhh[cg0],        bhr1 = bhh[cg1];
  const float bhz0 = bhh[HH + cg0],   bhz1 = bhh[HH + cg1];
  const float bhn0 = bhh[2*HH + cg0], bhn1 = bhh[2*HH + cg1];

  float hold[2][4];
#pragma unroll
  for (int g = 0; g < 2; ++g)
#pragma unroll
    for (int r = 0; r < 4; ++r) hold[g][r] = 0.f;

  // zero h buffer 0
  for (int e = tid; e < SPB2 * HSTR; e += 1024)
    hsbuf[0][e / HSTR][e % HSTR] = (_Float16)0.f;
  __syncthreads();

  for (int t = 0; t < TT; ++t) {
    const int cb = t & 1;
    const int nb = cb ^ 1;

    // ---- issue gi loads for this step (consumed after MFMA phase) ----
    float gir[2][4], giz[2][4], gin[2][4];
#pragma unroll
    for (int r = 0; r < 4; ++r) {
      const float* p0 = gi + ((size_t)(seq0 + mrow + r) * TT + t) * G3;
      gir[0][r] = __builtin_nontemporal_load(p0 + cg0);
      giz[0][r] = __builtin_nontemporal_load(p0 + HH + cg0);
      gin[0][r] = __builtin_nontemporal_load(p0 + 2 * HH + cg0);
      gir[1][r] = __builtin_nontemporal_load(p0 + cg1);
      giz[1][r] = __builtin_nontemporal_load(p0 + HH + cg1);
      gin[1][r] = __builtin_nontemporal_load(p0 + 2 * HH + cg1);
    }

    // ---- MFMA phase: 6 tiles, K=512 ----
    f32x4 acc0 = {0.f,0.f,0.f,0.f}, acc1 = {0.f,0.f,0.f,0.f}, acc2 = {0.f,0.f,0.f,0.f};
    f32x4 acc3 = {0.f,0.f,0.f,0.f}, acc4 = {0.f,0.f,0.f,0.f}, acc5 = {0.f,0.f,0.f,0.f};
#pragma unroll
    for (int kc = 0; kc < 16; ++kc) {
      f16x8 a = *reinterpret_cast<const f16x8*>(&hsbuf[cb][arow][kc * 32 + agrp * 8]);
      acc0 = __builtin_amdgcn_mfma_f32_16x16x32_f16(a, wb[0][kc], acc0, 0, 0, 0);
      acc1 = __builtin_amdgcn_mfma_f32_16x16x32_f16(a, wb[1][kc], acc1, 0, 0, 0);
      acc2 = __builtin_amdgcn_mfma_f32_16x16x32_f16(a, wb[2][kc], acc2, 0, 0, 0);
      acc3 = __builtin_amdgcn_mfma_f32_16x16x32_f16(a, wb[3][kc], acc3, 0, 0, 0);
      acc4 = __builtin_amdgcn_mfma_f32_16x16x32_f16(a, wb[4][kc], acc4, 0, 0, 0);
      acc5 = __builtin_amdgcn_mfma_f32_16x16x32_f16(a, wb[5][kc], acc5, 0, 0, 0);
    }

    // ---- register-local gate epilogue: 2 groups x 4 seqs per lane ----
#pragma unroll
    for (int r = 0; r < 4; ++r) {
      // group 0: tiles w (r-gate), w+32 (z), w+64 (n)
      {
        float hr = acc0[r] + bhr0;
        float hz = acc1[r] + bhz0;
        float hn = acc2[r] + bhn0;
        float rr = __builtin_amdgcn_rcpf(1.f + __expf(-(gir[0][r] + hr)));
        float zz = __builtin_amdgcn_rcpf(1.f + __expf(-(giz[0][r] + hz)));
        float ex = __expf(2.f * (gin[0][r] + rr * hn));
        float nn = 1.f - 2.f * __builtin_amdgcn_rcpf(ex + 1.f);
        float hnew = nn + zz * (hold[0][r] - nn);
        hold[0][r] = hnew;
        hsbuf[nb][mrow + r][cg0] = (_Float16)hnew;
        if (yout)
          __builtin_nontemporal_store(hnew, yout + ((size_t)(seq0 + mrow + r) * TT + t) * HH + cg0);
      }
      // group 1: tiles w+16, w+48, w+80
      {
        float hr = acc3[r] + bhr1;
        float hz = acc4[r] + bhz1;
        float hn = acc5[r] + bhn1;
        float rr = __builtin_amdgcn_rcpf(1.f + __expf(-(gir[1][r] + hr)));
        float zz = __builtin_amdgcn_rcpf(1.f + __expf(-(giz[1][r] + hz)));
        float ex = __expf(2.f * (gin[1][r] + rr * hn));
        float nn = 1.f - 2.f * __builtin_amdgcn_rcpf(ex + 1.f);
        float hnew = nn + zz * (hold[1][r] - nn);
        hold[1][r] = hnew;
        hsbuf[nb][mrow + r][cg1] = (_Float16)hnew;
        if (yout)
          __builtin_nontemporal_store(hnew, yout + ((size_t)(seq0 + mrow + r) * TT + t) * HH + cg1);
      }
    }
    __syncthreads();   // next-h buffer complete before next step reads it
  }

#pragma unroll
  for (int r = 0; r < 4; ++r) {
    hfin[(size_t)(seq0 + mrow + r) * HH + cg0] = hold[0][r];
    hfin[(size_t)(seq0 + mrow + r) * HH + cg1] = hold[1][r];
  }
}

// ---------------- fallback fp32 scan (row-streaming) ----------------
#define QS 4
#define SCTH 512
__global__ __launch_bounds__(SCTH) void gru_scan2f(
    const float* __restrict__ gi, const float* __restrict__ W,
    const float* __restrict__ bhh, float* __restrict__ hfin,
    float* __restrict__ yout)
{
  __shared__ __align__(16) float hs[HH][QS];
  const int col = threadIdx.x;
  const int seq0 = blockIdx.x * QS;
  const float bh0 = bhh[col];
  const float bh1 = bhh[HH + col];
  const float bh2 = bhh[2 * HH + col];
  const float* w0p = W + (size_t)col * HH;
  const float* w1p = W + (size_t)(HH + col) * HH;
  const float* w2p = W + (size_t)(2 * HH + col) * HH;

  *reinterpret_cast<float4*>(&hs[col][0]) = make_float4(0.f, 0.f, 0.f, 0.f);
  __syncthreads();

  for (int t = 0; t < TT; ++t) {
    float acc0[QS], acc1[QS], acc2[QS];
#pragma unroll
    for (int s = 0; s < QS; ++s) { acc0[s] = bh0; acc1[s] = bh1; acc2[s] = bh2; }
    float4 ho = *reinterpret_cast<const float4*>(&hs[col][0]);
    float hold[QS] = {ho.x, ho.y, ho.z, ho.w};
#pragma unroll 2
    for (int k0 = 0; k0 < HH; k0 += 4) {
      float w[3][4];
      float4 a = *reinterpret_cast<const float4*>(&w0p[k0]);
      w[0][0] = a.x; w[0][1] = a.y; w[0][2] = a.z; w[0][3] = a.w;
      float4 b = *reinterpret_cast<const float4*>(&w1p[k0]);
      w[1][0] = b.x; w[1][1] = b.y; w[1][2] = b.z; w[1][3] = b.w;
      float4 c = *reinterpret_cast<const float4*>(&w2p[k0]);
      w[2][0] = c.x; w[2][1] = c.y; w[2][2] = c.z; w[2][3] = c.w;
#pragma unroll
      for (int kk = 0; kk < 4; ++kk) {
        float4 h4 = *reinterpret_cast<const float4*>(&hs[k0 + kk][0]);
        float hq[4] = {h4.x, h4.y, h4.z, h4.w};
#pragma unroll
        for (int s = 0; s < QS; ++s) {
          acc0[s] = fmaf(hq[s], w[0][kk], acc0[s]);
          acc1[s] = fmaf(hq[s], w[1][kk], acc1[s]);
          acc2[s] = fmaf(hq[s], w[2][kk], acc2[s]);
        }
      }
    }
    __syncthreads();
    float hnew[QS];
#pragma unroll
    for (int s = 0; s < QS; ++s) {
      size_t grow = ((size_t)(seq0 + s) * TT + t) * G3;
      float ir = gi[grow + col];
      float iz = gi[grow + HH + col];
      float inn = gi[grow + 2 * HH + col];
      float r = 1.f / (1.f + expf(-(ir + acc0[s])));
      float z = 1.f / (1.f + expf(-(iz + acc1[s])));
      float nn = tanhf(inn + r * acc2[s]);
      hnew[s] = (1.f - z) * nn + z * hold[s];
      if (yout) yout[((size_t)(seq0 + s) * TT + t) * HH + col] = hnew[s];
    }
    *reinterpret_cast<float4*>(&hs[col][0]) =
        make_float4(hnew[0], hnew[1], hnew[2], hnew[3]);
    __syncthreads();
  }
#pragma unroll
  for (int s = 0; s < QS; ++s)
    hfin[(size_t)(seq0 + s) * HH + col] = hs[col][s];
}

// ---------------- final FC + channel mean ----------------
__global__ __launch_bounds__(256) void fc_mean(
    const float* __restrict__ hfin, const float* __restrict__ fcW,
    const float* __restrict__ fcb, float* __restrict__ out)
{
  __shared__ float red[256];
  const int b = blockIdx.x;
  const int tid = threadIdx.x;
  float sum = 0.f;
  for (int e = tid; e < CC * HH; e += 256) {
    int c = e >> 9;
    int k = e & (HH - 1);
    sum += hfin[(size_t)(b * CC + c) * HH + k] * fcW[k];
  }
  red[tid] = sum;
  __syncthreads();
  for (int w = 128; w > 0; w >>= 1) {
    if (tid < w) red[tid] += red[tid + w];
    __syncthreads();
  }
  if (tid == 0) out[b] = red[0] * (1.f / CC) + fcb[0];
}

extern "C" void kernel_launch(void* const* d_in, const int* in_sizes, int n_in,
                              void* d_out, int out_size, void* d_ws, size_t ws_size,
                              hipStream_t stream)
{
  const float* x    = (const float*)d_in[0];
  const float* Wih0 = (const float*)d_in[1];
  const float* Whh0 = (const float*)d_in[2];
  const float* bih0 = (const float*)d_in[3];
  const float* bhh0 = (const float*)d_in[4];
  const float* Wih1 = (const float*)d_in[5];
  const float* Whh1 = (const float*)d_in[6];
  const float* bih1 = (const float*)d_in[7];
  const float* bhh1 = (const float*)d_in[8];
  const float* fcW  = (const float*)d_in[9];
  const float* fcb  = (const float*)d_in[10];
  float* out = (float*)d_out;

  // ws layout:
  //   gi   [MROWS][G3] fp32   100,663,296 @ 0
  //   y0   [MROWS][HH] fp32    33,554,432 @ 100,663,296
  //   hfin [NSEQ][HH]  fp32       524,288 @ 134,217,728
  //   pack fp16 1-plane         1,572,864 @ 134,742,016   (end 136,314,880)
  char* ws = (char*)d_ws;
  float* gibuf = (float*)ws;
  float* y0    = (float*)(ws + 100663296ull);
  float* hfin  = (float*)(ws + 134217728ull);
  _Float16* packb = (_Float16*)(ws + 134742016ull);
  const bool mfma_ok = (ws_size >= 136314880ull);

  // layer 0 input GEMM
  gemm_bias<<<dim3(G3 / TNg, MROWS / TMg), 256, 0, stream>>>(x, Wih0, bih0, gibuf, MROWS, G3, FF);

  if (mfma_ok) {
    pack_whh<<<dim3(384), 256, 0, stream>>>(Whh0, packb);
    gru_scan_mfma<<<dim3(NSEQ / SPB2), 1024, 0, stream>>>(gibuf, packb, bhh0, hfin, y0);
  } else {
    gru_scan2f<<<dim3(NSEQ / QS), SCTH, 0, stream>>>(gibuf, Whh0, bhh0, hfin, y0);
  }

  // layer 1 input GEMM (gi reused)
  gemm_bias<<<dim3(G3 / TNg, MROWS / TMg), 256, 0, stream>>>(y0, Wih1, bih1, gibuf, MROWS, G3, HH);

  if (mfma_ok) {
    pack_whh<<<dim3(384), 256, 0, stream>>>(Whh1, packb);
    gru_scan_mfma<<<dim3(NSEQ / SPB2), 1024, 0, stream>>>(gibuf, packb, bhh1, hfin, nullptr);
  } else {
    gru_scan2f<<<dim3(NSEQ / QS), SCTH, 0, stream>>>(gibuf, Whh1, bhh1, hfin, nullptr);
  }

  fc_mean<<<dim3(BB), 256, 0, stream>>>(hfin, fcW, fcb, out);
}

// Round 6
// 5752.941 us; speedup vs baseline: 2.5814x; 1.0040x over previous
//
#include <hip/hip_runtime.h>
#include <math.h>

// Problem dims (fixed by reference)
#define BB 32
#define CC 8
#define TT 64
#define FF 256
#define HH 512
#define G3 1536
#define NSEQ 256            // BB*CC
#define MROWS 16384         // NSEQ*TT

typedef _Float16 f16x8 __attribute__((ext_vector_type(8)));
typedef float f32x4 __attribute__((ext_vector_type(4)));

// ---------------- input GEMM: C[M][N] = A[M][K] @ W[N][K]^T + bias[N] ----------------
#define TMg 128
#define TNg 128
#define TKg 16

__global__ __launch_bounds__(256) void gemm_bias(
    const float* __restrict__ A, const float* __restrict__ W,
    const float* __restrict__ bias, float* __restrict__ C,
    int M, int N, int K)
{
  __shared__ float As[TKg][TMg + 4];
  __shared__ float Ws[TKg][TNg + 4];
  const int bm = blockIdx.y * TMg;
  const int bn = blockIdx.x * TNg;
  const int tid = threadIdx.x;
  const int tx = tid & 15;
  const int ty = tid >> 4;
  float acc[8][8];
#pragma unroll
  for (int i = 0; i < 8; ++i)
#pragma unroll
    for (int j = 0; j < 8; ++j) acc[i][j] = 0.f;

  for (int k0 = 0; k0 < K; k0 += TKg) {
    __syncthreads();
#pragma unroll
    for (int i = 0; i < 8; ++i) {
      int e = i * 256 + tid;
      int r = e >> 4;
      int c = e & 15;
      As[c][r] = A[(size_t)(bm + r) * K + (k0 + c)];
      Ws[c][r] = W[(size_t)(bn + r) * K + (k0 + c)];
    }
    __syncthreads();
#pragma unroll
    for (int k = 0; k < TKg; ++k) {
      float a[8], w[8];
#pragma unroll
      for (int i = 0; i < 8; ++i) a[i] = As[k][ty * 8 + i];
#pragma unroll
      for (int j = 0; j < 8; ++j) w[j] = Ws[k][tx + 16 * j];
#pragma unroll
      for (int i = 0; i < 8; ++i)
#pragma unroll
        for (int j = 0; j < 8; ++j) acc[i][j] = fmaf(a[i], w[j], acc[i][j]);
    }
  }
#pragma unroll
  for (int i = 0; i < 8; ++i) {
    size_t m = (size_t)(bm + ty * 8 + i);
#pragma unroll
    for (int j = 0; j < 8; ++j) {
      int n = bn + tx + 16 * j;
      C[m * N + n] = acc[i][j] + bias[n];
    }
  }
}

// ---------------- pack Whh[G3][HH] fp32 -> single fp16 plane, B-fragment order --------
// P[tile(96)][kc(16)][lane(64)][8 f16]
// B-frag (16x16x32_f16): n = lane&15 (Whh row within tile), k = kc*32 + (lane>>4)*8 + i
__global__ __launch_bounds__(256) void pack_whh(
    const float* __restrict__ W, _Float16* __restrict__ P)
{
  int id = blockIdx.x * 256 + threadIdx.x;    // 0 .. 98303
  int lane = id & 63;
  int kc = (id >> 6) & 15;
  int tile = id >> 10;                        // 0..95
  int row = tile * 16 + (lane & 15);
  int k0 = kc * 32 + ((lane >> 4) * 8);
  const float* src = W + (size_t)row * HH + k0;
  f16x8 hi;
#pragma unroll
  for (int i = 0; i < 8; ++i) hi[i] = (_Float16)src[i];
  *reinterpret_cast<f16x8*>(P + ((size_t)(tile * 16 + kc) * 64 + lane) * 8) = hi;
}

// ---------------- MFMA recurrent scan, register double-buffered weight stream --------
// 16 blocks x 16 seqs x 1024 threads (16 waves = 4/SIMD forced co-resident).
// Wave w owns tiles {w, w+32, w+64, w+16, w+48, w+80}: r/z/n gates of column
// groups w and w+16 -> gate epilogue is register-local per lane.
// Weights stream from L2 every step through a named 2-buffer register pipeline
// (16 dwordx4 in flight per wave while the previous tile's 16-MFMA chain runs).
// __launch_bounds__(1024,4): honest 4 waves/EU declaration => 512-VGPR cap.
// h state: fp16, LDS double-buffered, stride 520 (2-way = conflict-free b128).
#define SPB2 16
#define HSTR 520

#define LOADT(buf, ti)                                                          \
  {                                                                             \
    const _Float16* _s = packW + ((size_t)(ti) * 16 * 64 + lane) * 8;           \
    _Pragma("unroll")                                                           \
    for (int kc = 0; kc < 16; ++kc)                                             \
      buf[kc] = *reinterpret_cast<const f16x8*>(_s + (size_t)kc * 512);         \
  }

#define MFMA16(buf, acc)                                                        \
  {                                                                             \
    _Pragma("unroll")                                                           \
    for (int kc = 0; kc < 16; ++kc)                                             \
      acc = __builtin_amdgcn_mfma_f32_16x16x32_f16(af[kc], buf[kc], acc, 0, 0, 0); \
  }

__global__ __launch_bounds__(1024, 4) void gru_scan_mfma(
    const float* __restrict__ gi,      // [NSEQ][TT][G3]
    const _Float16* __restrict__ packW,
    const float* __restrict__ bhh,     // [G3]
    float* __restrict__ hfin,          // [NSEQ][HH]
    float* __restrict__ yout)          // [NSEQ][TT][HH] or nullptr
{
  __shared__ _Float16 hsbuf[2][SPB2][HSTR];   // 33.3 KB

  const int tid = threadIdx.x;
  const int lane = tid & 63;
  const int wid = tid >> 6;                   // 0..15
  const int seq0 = blockIdx.x * SPB2;

  const int arow = lane & 15;                 // A-frag row (seq)
  const int agrp = lane >> 4;
  const int dcol = lane & 15;                 // D-frag col within tile
  const int mrow = (lane >> 4) * 4;           // D-frag first row (seq)

  const int cg0 = wid * 16 + dcol;            // column group w
  const int cg1 = cg0 + 256;                  // column group w+16

  const int t0 = wid;        // r-gate, group0
  const int t1 = wid + 32;   // z-gate, group0
  const int t2 = wid + 64;   // n-gate, group0
  const int t3 = wid + 16;   // r-gate, group1
  const int t4 = wid + 48;   // z-gate, group1
  const int t5 = wid + 80;   // n-gate, group1

  // biases for this lane's two columns, all 3 gates
  const float bhr0 = bhh[cg0],        bhr1 = bhh[cg1];
  const float bhz0 = bhh[HH + cg0],   bhz1 = bhh[HH + cg1];
  const float bhn0 = bhh[2*HH + cg0], bhn1 = bhh[2*HH + cg1];

  float hold[2][4];
#pragma unroll
  for (int g = 0; g < 2; ++g)
#pragma unroll
    for (int r = 0; r < 4; ++r) hold[g][r] = 0.f;

  // zero h buffer 0
  for (int e = tid; e < SPB2 * HSTR; e += 1024)
    hsbuf[0][e / HSTR][e % HSTR] = (_Float16)0.f;
  __syncthreads();

  for (int t = 0; t < TT; ++t) {
    const int cb = t & 1;
    const int nb = cb ^ 1;

    // ---- issue gi loads for this step (consumed in epilogue) ----
    float gir[2][4], giz[2][4], gin[2][4];
#pragma unroll
    for (int r = 0; r < 4; ++r) {
      const float* p0 = gi + ((size_t)(seq0 + mrow + r) * TT + t) * G3;
      gir[0][r] = __builtin_nontemporal_load(p0 + cg0);
      giz[0][r] = __builtin_nontemporal_load(p0 + HH + cg0);
      gin[0][r] = __builtin_nontemporal_load(p0 + 2 * HH + cg0);
      gir[1][r] = __builtin_nontemporal_load(p0 + cg1);
      giz[1][r] = __builtin_nontemporal_load(p0 + HH + cg1);
      gin[1][r] = __builtin_nontemporal_load(p0 + 2 * HH + cg1);
    }

    // ---- A fragments for this step's h ----
    f16x8 af[16];
#pragma unroll
    for (int kc = 0; kc < 16; ++kc)
      af[kc] = *reinterpret_cast<const f16x8*>(&hsbuf[cb][arow][kc * 32 + agrp * 8]);

    // ---- 6-tile MFMA pipeline, named 2-buffer weight stream ----
    f16x8 bufA[16], bufB[16];
    f32x4 acc0 = {0.f,0.f,0.f,0.f}, acc1 = {0.f,0.f,0.f,0.f}, acc2 = {0.f,0.f,0.f,0.f};
    f32x4 acc3 = {0.f,0.f,0.f,0.f}, acc4 = {0.f,0.f,0.f,0.f}, acc5 = {0.f,0.f,0.f,0.f};

    LOADT(bufA, t0)
    LOADT(bufB, t1)      // in flight during tile-0 MFMA chain
    MFMA16(bufA, acc0)
    LOADT(bufA, t2)
    MFMA16(bufB, acc1)
    LOADT(bufB, t3)
    MFMA16(bufA, acc2)
    LOADT(bufA, t4)
    MFMA16(bufB, acc3)
    LOADT(bufB, t5)
    MFMA16(bufA, acc4)
    MFMA16(bufB, acc5)

    // ---- register-local gate epilogue: 2 groups x 4 seqs per lane ----
#pragma unroll
    for (int r = 0; r < 4; ++r) {
      {
        float hr = acc0[r] + bhr0;
        float hz = acc1[r] + bhz0;
        float hn = acc2[r] + bhn0;
        float rr = __builtin_amdgcn_rcpf(1.f + __expf(-(gir[0][r] + hr)));
        float zz = __builtin_amdgcn_rcpf(1.f + __expf(-(giz[0][r] + hz)));
        float ex = __expf(2.f * (gin[0][r] + rr * hn));
        float nn = 1.f - 2.f * __builtin_amdgcn_rcpf(ex + 1.f);
        float hnew = nn + zz * (hold[0][r] - nn);
        hold[0][r] = hnew;
        hsbuf[nb][mrow + r][cg0] = (_Float16)hnew;
        if (yout)
          __builtin_nontemporal_store(hnew, yout + ((size_t)(seq0 + mrow + r) * TT + t) * HH + cg0);
      }
      {
        float hr = acc3[r] + bhr1;
        float hz = acc4[r] + bhz1;
        float hn = acc5[r] + bhn1;
        float rr = __builtin_amdgcn_rcpf(1.f + __expf(-(gir[1][r] + hr)));
        float zz = __builtin_amdgcn_rcpf(1.f + __expf(-(giz[1][r] + hz)));
        float ex = __expf(2.f * (gin[1][r] + rr * hn));
        float nn = 1.f - 2.f * __builtin_amdgcn_rcpf(ex + 1.f);
        float hnew = nn + zz * (hold[1][r] - nn);
        hold[1][r] = hnew;
        hsbuf[nb][mrow + r][cg1] = (_Float16)hnew;
        if (yout)
          __builtin_nontemporal_store(hnew, yout + ((size_t)(seq0 + mrow + r) * TT + t) * HH + cg1);
      }
    }
    __syncthreads();   // next-h buffer complete before next step reads it
  }

#pragma unroll
  for (int r = 0; r < 4; ++r) {
    hfin[(size_t)(seq0 + mrow + r) * HH + cg0] = hold[0][r];
    hfin[(size_t)(seq0 + mrow + r) * HH + cg1] = hold[1][r];
  }
}

// ---------------- fallback fp32 scan (row-streaming) ----------------
#define QS 4
#define SCTH 512
__global__ __launch_bounds__(SCTH) void gru_scan2f(
    const float* __restrict__ gi, const float* __restrict__ W,
    const float* __restrict__ bhh, float* __restrict__ hfin,
    float* __restrict__ yout)
{
  __shared__ __align__(16) float hs[HH][QS];
  const int col = threadIdx.x;
  const int seq0 = blockIdx.x * QS;
  const float bh0 = bhh[col];
  const float bh1 = bhh[HH + col];
  const float bh2 = bhh[2 * HH + col];
  const float* w0p = W + (size_t)col * HH;
  const float* w1p = W + (size_t)(HH + col) * HH;
  const float* w2p = W + (size_t)(2 * HH + col) * HH;

  *reinterpret_cast<float4*>(&hs[col][0]) = make_float4(0.f, 0.f, 0.f, 0.f);
  __syncthreads();

  for (int t = 0; t < TT; ++t) {
    float acc0[QS], acc1[QS], acc2[QS];
#pragma unroll
    for (int s = 0; s < QS; ++s) { acc0[s] = bh0; acc1[s] = bh1; acc2[s] = bh2; }
    float4 ho = *reinterpret_cast<const float4*>(&hs[col][0]);
    float hold[QS] = {ho.x, ho.y, ho.z, ho.w};
#pragma unroll 2
    for (int k0 = 0; k0 < HH; k0 += 4) {
      float w[3][4];
      float4 a = *reinterpret_cast<const float4*>(&w0p[k0]);
      w[0][0] = a.x; w[0][1] = a.y; w[0][2] = a.z; w[0][3] = a.w;
      float4 b = *reinterpret_cast<const float4*>(&w1p[k0]);
      w[1][0] = b.x; w[1][1] = b.y; w[1][2] = b.z; w[1][3] = b.w;
      float4 c = *reinterpret_cast<const float4*>(&w2p[k0]);
      w[2][0] = c.x; w[2][1] = c.y; w[2][2] = c.z; w[2][3] = c.w;
#pragma unroll
      for (int kk = 0; kk < 4; ++kk) {
        float4 h4 = *reinterpret_cast<const float4*>(&hs[k0 + kk][0]);
        float hq[4] = {h4.x, h4.y, h4.z, h4.w};
#pragma unroll
        for (int s = 0; s < QS; ++s) {
          acc0[s] = fmaf(hq[s], w[0][kk], acc0[s]);
          acc1[s] = fmaf(hq[s], w[1][kk], acc1[s]);
          acc2[s] = fmaf(hq[s], w[2][kk], acc2[s]);
        }
      }
    }
    __syncthreads();
    float hnew[QS];
#pragma unroll
    for (int s = 0; s < QS; ++s) {
      size_t grow = ((size_t)(seq0 + s) * TT + t) * G3;
      float ir = gi[grow + col];
      float iz = gi[grow + HH + col];
      float inn = gi[grow + 2 * HH + col];
      float r = 1.f / (1.f + expf(-(ir + acc0[s])));
      float z = 1.f / (1.f + expf(-(iz + acc1[s])));
      float nn = tanhf(inn + r * acc2[s]);
      hnew[s] = (1.f - z) * nn + z * hold[s];
      if (yout) yout[((size_t)(seq0 + s) * TT + t) * HH + col] = hnew[s];
    }
    *reinterpret_cast<float4*>(&hs[col][0]) =
        make_float4(hnew[0], hnew[1], hnew[2], hnew[3]);
    __syncthreads();
  }
#pragma unroll
  for (int s = 0; s < QS; ++s)
    hfin[(size_t)(seq0 + s) * HH + col] = hs[col][s];
}

// ---------------- final FC + channel mean ----------------
__global__ __launch_bounds__(256) void fc_mean(
    const float* __restrict__ hfin, const float* __restrict__ fcW,
    const float* __restrict__ fcb, float* __restrict__ out)
{
  __shared__ float red[256];
  const int b = blockIdx.x;
  const int tid = threadIdx.x;
  float sum = 0.f;
  for (int e = tid; e < CC * HH; e += 256) {
    int c = e >> 9;
    int k = e & (HH - 1);
    sum += hfin[(size_t)(b * CC + c) * HH + k] * fcW[k];
  }
  red[tid] = sum;
  __syncthreads();
  for (int w = 128; w > 0; w >>= 1) {
    if (tid < w) red[tid] += red[tid + w];
    __syncthreads();
  }
  if (tid == 0) out[b] = red[0] * (1.f / CC) + fcb[0];
}

extern "C" void kernel_launch(void* const* d_in, const int* in_sizes, int n_in,
                              void* d_out, int out_size, void* d_ws, size_t ws_size,
                              hipStream_t stream)
{
  const float* x    = (const float*)d_in[0];
  const float* Wih0 = (const float*)d_in[1];
  const float* Whh0 = (const float*)d_in[2];
  const float* bih0 = (const float*)d_in[3];
  const float* bhh0 = (const float*)d_in[4];
  const float* Wih1 = (const float*)d_in[5];
  const float* Whh1 = (const float*)d_in[6];
  const float* bih1 = (const float*)d_in[7];
  const float* bhh1 = (const float*)d_in[8];
  const float* fcW  = (const float*)d_in[9];
  const float* fcb  = (const float*)d_in[10];
  float* out = (float*)d_out;

  // ws layout:
  //   gi   [MROWS][G3] fp32   100,663,296 @ 0
  //   y0   [MROWS][HH] fp32    33,554,432 @ 100,663,296
  //   hfin [NSEQ][HH]  fp32       524,288 @ 134,217,728
  //   pack fp16 1-plane         1,572,864 @ 134,742,016   (end 136,314,880)
  char* ws = (char*)d_ws;
  float* gibuf = (float*)ws;
  float* y0    = (float*)(ws + 100663296ull);
  float* hfin  = (float*)(ws + 134217728ull);
  _Float16* packb = (_Float16*)(ws + 134742016ull);
  const bool mfma_ok = (ws_size >= 136314880ull);

  // layer 0 input GEMM
  gemm_bias<<<dim3(G3 / TNg, MROWS / TMg), 256, 0, stream>>>(x, Wih0, bih0, gibuf, MROWS, G3, FF);

  if (mfma_ok) {
    pack_whh<<<dim3(384), 256, 0, stream>>>(Whh0, packb);
    gru_scan_mfma<<<dim3(NSEQ / SPB2), 1024, 0, stream>>>(gibuf, packb, bhh0, hfin, y0);
  } else {
    gru_scan2f<<<dim3(NSEQ / QS), SCTH, 0, stream>>>(gibuf, Whh0, bhh0, hfin, y0);
  }

  // layer 1 input GEMM (gi reused)
  gemm_bias<<<dim3(G3 / TNg, MROWS / TMg), 256, 0, stream>>>(y0, Wih1, bih1, gibuf, MROWS, G3, HH);

  if (mfma_ok) {
    pack_whh<<<dim3(384), 256, 0, stream>>>(Whh1, packb);
    gru_scan_mfma<<<dim3(NSEQ / SPB2), 1024, 0, stream>>>(gibuf, packb, bhh1, hfin, nullptr);
  } else {
    gru_scan2f<<<dim3(NSEQ / QS), SCTH, 0, stream>>>(gibuf, Whh1, bhh1, hfin, nullptr);
  }

  fc_mean<<<dim3(BB), 256, 0, stream>>>(hfin, fcW, fcb, out);
}